// Round 13
// baseline (380.840 us; speedup 1.0000x reference)
//
#include <hip/hip_runtime.h>

typedef unsigned short u16;
typedef unsigned int u32;
typedef _Float16 f16;
typedef f16 f16x8 __attribute__((ext_vector_type(8)));
typedef float f32x4 __attribute__((ext_vector_type(4)));

__device__ __forceinline__ float h2f(f16 h){ return (float)h; }
__device__ __forceinline__ f16 f2h(float f){ return (f16)f; }

__device__ __forceinline__ f16x8 ldfrag(const f16* p){
  union { uint4 u; f16x8 h; } x;
  x.u = *(const uint4*)p;
  return x.h;
}
__device__ __forceinline__ void gload_lds16(const f16* g, f16* l){
  __builtin_amdgcn_global_load_lds(
      (const __attribute__((address_space(1))) u32*)g,
      (__attribute__((address_space(3))) u32*)l, 16, 0, 0);
}

template<int N> __device__ __forceinline__ void wait_vmcnt(){
  if constexpr      (N == 0)  asm volatile("s_waitcnt vmcnt(0)"  ::: "memory");
  else if constexpr (N == 4)  asm volatile("s_waitcnt vmcnt(4)"  ::: "memory");
  else if constexpr (N == 6)  asm volatile("s_waitcnt vmcnt(6)"  ::: "memory");
  else if constexpr (N == 8)  asm volatile("s_waitcnt vmcnt(8)"  ::: "memory");
  else if constexpr (N == 12) asm volatile("s_waitcnt vmcnt(12)" ::: "memory");
  else static_assert(N == 0, "unsupported vmcnt");
}

// ---------------- CSR build (merged) ----------------

__global__ void csr_init(const int* __restrict__ ei, int* __restrict__ flag,
                         int* __restrict__ cnt, int* __restrict__ fillpos, int n){
  int i = blockIdx.x * blockDim.x + threadIdx.x;
  if (i == 0){
    int orv = 0;
    for (int k = 0; k < 200; k++) orv |= ei[2*k + 1];
    *flag = (orv == 0) ? 1 : 0;      // int64 edge_index -> high words all 0
  }
  if (i < n){ cnt[i] = 1; fillpos[i] = 1; }   // slot 0 = self loop
}

__global__ void count_edges(const int* __restrict__ ei, int E, const int* __restrict__ flag,
                            int* __restrict__ cnt){
  int e = blockIdx.x * blockDim.x + threadIdx.x;
  if (e >= E) return;
  int dst = (*flag) ? ei[2*E + 2*e] : ei[E + e];
  atomicAdd(&cnt[dst], 1);
}

#define SCAN_T 1024
__global__ void scan_kernel(const int* __restrict__ cnt, int* __restrict__ row_ptr, int n){
  __shared__ int sm[SCAN_T];
  int t = threadIdx.x;
  int chunk = (n + SCAN_T - 1) / SCAN_T;
  int lo = t * chunk, hi = lo + chunk; if (hi > n) hi = n; if (lo > n) lo = n;
  int s = 0;
  for (int i = lo; i < hi; i++) s += cnt[i];
  sm[t] = s; __syncthreads();
  for (int off = 1; off < SCAN_T; off <<= 1){
    int v = (t >= off) ? sm[t - off] : 0;
    __syncthreads();
    sm[t] += v;
    __syncthreads();
  }
  int base = sm[t] - s;
  for (int i = lo; i < hi; i++){ row_ptr[i] = base; base += cnt[i]; }
  if (t == 0) row_ptr[n] = sm[SCAN_T - 1];
}

__global__ void loop_fill(const int* __restrict__ ei, int E, const int* __restrict__ flag,
                          const int* __restrict__ row_ptr, int* __restrict__ fillpos,
                          int* __restrict__ col, int n){
  int i = blockIdx.x * blockDim.x + threadIdx.x;
  if (i < n) col[row_ptr[i]] = i;          // self loop at slot 0
  if (i < E){
    int f = *flag;
    int src = f ? ei[2*i]       : ei[i];
    int dst = f ? ei[2*E + 2*i] : ei[E + i];
    int off = atomicAdd(&fillpos[dst], 1); // starts at 1: disjoint from slot 0
    col[row_ptr[dst] + off] = src;
  }
}

// ---------------- merged prep: x->fp16 + all 4 weight transposes ----------

__global__ __launch_bounds__(256) void prep_kernel(
    const float* __restrict__ x, f16* __restrict__ xh, int nx, int nbx,
    const float* __restrict__ Win, f16* __restrict__ Twin,
    const float* __restrict__ W1, f16* __restrict__ T1,
    const float* __restrict__ W2, f16* __restrict__ T2,
    const float* __restrict__ W3, f16* __restrict__ T3)
{
  int b = blockIdx.x;
  int tid = threadIdx.x;
  if (b < nbx){
    int i = b * 256 + tid;
    if (i < nx) xh[i] = f2h(x[i]);
    return;
  }
  b -= nbx;
  const float* W; f16* T; int K, N;
  if (b < 4)              { W = Win; T = Twin; K = 32;   N = 128;  }
  else if ((b -= 4) < 256){ W = W1;  T = T1;   K = 128;  N = 2048; }
  else if ((b -= 256) < 4096){ W = W2; T = T2; K = 2048; N = 2048; }
  else { b -= 4096;         W = W3;  T = T3;   K = 2048; N = 512;  }
  int kbn = K / 32;
  int kb = (b % kbn) * 32, nb = (b / kbn) * 32;
  __shared__ float sm[32][33];
  int tx = tid & 31, ty = tid >> 5;
  for (int i = 0; i < 32; i += 8)
    sm[ty + i][tx] = W[(size_t)(kb + ty + i) * N + nb + tx];
  __syncthreads();
  for (int i = 0; i < 32; i += 8)
    T[(size_t)(nb + ty + i) * K + kb + tx] = f2h(sm[tx][ty + i]);
}

// ---------------- fp16 MFMA GEMM, 3-deep dbuf + counted vmcnt, swizzled ---
// C[M][N] = A[M][K] @ B[K][N]; A row-major fp16 (M padded to x128), B WT[N][K].
// Tile 128 x (FJ*32); 4 waves 2x2. BK=32 big-N layers, BK=64/FJ=2 for N=512.
// DEPTH-3 pipeline: prologue stages tiles 0,1; iter t stages tile t+2 then
// waits vmcnt(2*NL) -- only the oldest NL (tile t) must land; tiles t+1,t+2
// stay in flight so each load gets ~2 compute phases (~400cy) of cover vs
// the ~300-500cy L2/L3 latency the depth-2 loop exposed (R10: vmcnt(NL)
// covered one ~180cy phase only; MfmaUtil stuck at 31%).
// LDS 3x16KB=48KB (FJ4/BK32): keeps 3 blocks/CU co-residency.
// Correctness: barrier#1 after wait => buf[t%3] fully written by all waves;
// compiler lgkmcnt before MFMA => ds_reads done; barrier#2 => all waves done
// reading buf[t%3] before iter t+1's STAGE targets that same buffer.
// NO fused-alpha epilogue (R4 atomics, R11 registers: both lost ~40us).
// Swizzle both-sides (rule #21): verified 0 bank conflicts (R7-R12).
// EPI 0: fp32 C.  EPI 1: bias+lrelu -> fp16.  EPI 2: plain fp16.

template<int EPI, int FJ, int BK>
__global__ __launch_bounds__(256) void gemm_kernel(
    const f16* __restrict__ A, const f16* __restrict__ B,
    float* __restrict__ C, f16* __restrict__ Ch,
    const float* __restrict__ bias,
    int M, int N, int K, int nbm, int nbn)
{
  constexpr int BN  = FJ * 32;
  constexpr int TPR = BK / 8;
  constexpr int RPG = 256 / TPR;
  constexpr int NGA = 128 / RPG;
  constexpr int NGB = BN / RPG;
  constexpr int KS  = BK / 32;
  constexpr int NL  = NGA + NGB;

  __shared__ f16 sA[3][128 * BK];
  __shared__ f16 sB[3][BN * BK];

  // bijective XCD swizzle (m204)
  int nwg = nbm * nbn;
  int bid = blockIdx.x;
  int q = nwg >> 3, r = nwg & 7;
  int xcd = bid & 7, idx = bid >> 3;
  int wg = (xcd < r ? xcd * (q + 1) : r * (q + 1) + (xcd - r) * q) + idx;
  int bm = wg / nbn, bn = wg % nbn;

  int tid = threadIdx.x;
  int lane = tid & 63;
  int w = tid >> 6;
  int wr = (w >> 1) * 64, wc = (w & 1) * (FJ * 16);
  int lm = lane & 15;

  int slot = tid % TPR, rg = tid / TPR;
  int sk;
  if constexpr (BK == 64) sk = ((slot ^ (rg & 7))) * 8;
  else                    sk = ((slot ^ ((rg >> 1) & 3))) * 8;

  const f16* pA[NGA];
  const f16* pB[NGB];
  #pragma unroll
  for (int i = 0; i < NGA; i++)
    pA[i] = A + ((long)bm * 128 + rg + RPG * i) * K + sk;
  #pragma unroll
  for (int i = 0; i < NGB; i++)
    pB[i] = B + ((long)bn * BN + rg + RPG * i) * K + sk;

  auto STAGE = [&](int buf, int k0){
    #pragma unroll
    for (int i = 0; i < NGA; i++)
      gload_lds16(pA[i] + k0, &sA[buf][i * 2048 + tid * 8]);
    #pragma unroll
    for (int i = 0; i < NGB; i++)
      gload_lds16(pB[i] + k0, &sB[buf][i * 2048 + tid * 8]);
  };

  f32x4 acc[4][FJ] = {};

  int nt = K / BK;
  STAGE(0, 0);
  if (nt > 1) STAGE(1, BK);
  int cur = 0;
  for (int t = 0; t < nt; t++){
    if (t + 2 < nt){
      int nb2 = cur + 2; if (nb2 >= 3) nb2 -= 3;
      STAGE(nb2, (t + 2) * BK);
      wait_vmcnt<2 * NL>();           // oldest NL (tile t) complete
    } else if (t + 1 < nt){
      wait_vmcnt<NL>();
    } else {
      wait_vmcnt<0>();
    }
    __builtin_amdgcn_s_barrier();     // buf cur fully written by all waves
    __builtin_amdgcn_sched_barrier(0);

    f16x8 af[4][KS], bfr[FJ][KS];
    #pragma unroll
    for (int ks = 0; ks < KS; ks++){
      #pragma unroll
      for (int f = 0; f < 4; f++){
        int row = wr + f * 16 + lm;
        int phys;
        if constexpr (BK == 64) phys = (ks * 4 + (lane >> 4)) ^ (lm & 7);
        else                    phys = (lane >> 4) ^ ((lm >> 1) & 3);
        af[f][ks] = ldfrag(&sA[cur][row * BK + phys * 8]);
      }
      #pragma unroll
      for (int f = 0; f < FJ; f++){
        int row = wc + f * 16 + lm;
        int phys;
        if constexpr (BK == 64) phys = (ks * 4 + (lane >> 4)) ^ (lm & 7);
        else                    phys = (lane >> 4) ^ ((lm >> 1) & 3);
        bfr[f][ks] = ldfrag(&sB[cur][row * BK + phys * 8]);
      }
    }
    __builtin_amdgcn_s_setprio(1);
    #pragma unroll
    for (int ks = 0; ks < KS; ks++)
      #pragma unroll
      for (int fi = 0; fi < 4; fi++)
        #pragma unroll
        for (int fj = 0; fj < FJ; fj++)
          acc[fi][fj] = __builtin_amdgcn_mfma_f32_16x16x32_f16(
              af[fi][ks], bfr[fj][ks], acc[fi][fj], 0, 0, 0);
    __builtin_amdgcn_s_setprio(0);
    __builtin_amdgcn_sched_barrier(0);
    __builtin_amdgcn_s_barrier();     // reads of buf cur done before iter
                                      // t+1 STAGEs into this same buffer
    cur = (cur + 1 == 3) ? 0 : cur + 1;
  }

  // ---- store epilogue (M padded: no guards) ----
  #pragma unroll
  for (int fi = 0; fi < 4; fi++){
    int mb = bm * 128 + wr + fi * 16 + ((lane >> 4) << 2);
    #pragma unroll
    for (int fj = 0; fj < FJ; fj++){
      int n = bn * BN + wc + fj * 16 + lm;
      #pragma unroll
      for (int j = 0; j < 4; j++){
        int m = mb + j;
        float v = acc[fi][fj][j];
        size_t o = (size_t)m * N + n;
        if (EPI == 0){
          C[o] = v;
        } else if (EPI == 2){
          Ch[o] = f2h(v);
        } else {
          v += bias[n];
          v = v > 0.0f ? v : 0.2f * v;
          Ch[o] = f2h(v);
        }
      }
    }
  }
}

// ---------------- attention coefficients (fp16 H) ----------------

template<int HEADS, int CH>
__global__ __launch_bounds__(256) void alpha_kernel(
    const f16* __restrict__ H, const float* __restrict__ a_s, const float* __restrict__ a_d,
    float* __restrict__ asrc, float* __restrict__ adst, int Nn)
{
  int gw = blockIdx.x * 4 + (threadIdx.x >> 6);
  int lane = threadIdx.x & 63;
  int node = gw / HEADS, hd = gw % HEADS;
  if (node >= Nn) return;
  size_t base = (size_t)node * HEADS * CH + hd * CH;
  const float* asp = a_s + hd * CH;
  const float* adp = a_d + hd * CH;
  float s1 = 0.0f, s2 = 0.0f;
  #pragma unroll
  for (int i = 0; i < CH / 256; i++){
    int off = i * 256 + lane * 4;
    union { uint2 u; f16 h[4]; } x;
    x.u = *(const uint2*)(H + base + off);
    float4 s4 = *(const float4*)(asp + off);
    float4 d4 = *(const float4*)(adp + off);
    s1 += h2f(x.h[0]) * s4.x + h2f(x.h[1]) * s4.y + h2f(x.h[2]) * s4.z + h2f(x.h[3]) * s4.w;
    s2 += h2f(x.h[0]) * d4.x + h2f(x.h[1]) * d4.y + h2f(x.h[2]) * d4.z + h2f(x.h[3]) * d4.w;
  }
  for (int off = 32; off; off >>= 1){
    s1 += __shfl_xor(s1, off);
    s2 += __shfl_xor(s2, off);
  }
  if (lane == 0){ asrc[gw] = s1; adst[gw] = s2; }
}

// ---------------- fused segment-softmax + aggregation ----------------

template<int HEADS, int CH, bool FINAL>
__global__ __launch_bounds__(256) void smax_agg_kernel(
    const f16* __restrict__ H, const int* __restrict__ row_ptr,
    const int* __restrict__ col,
    const float* __restrict__ asrc, const float* __restrict__ adst,
    const float* __restrict__ bias, f16* __restrict__ Oh, float* __restrict__ Ofp)
{
  constexpr int F = HEADS * CH;
  constexpr int CPT = F / 256;
  __shared__ float s_m[HEADS], s_inv[HEADS];
  int dst = blockIdx.x;
  int t = threadIdx.x;
  int s = row_ptr[dst], e = row_ptr[dst + 1];

  if (t < 64){
    const int hd = (HEADS == 8) ? (t & 7) : 0;
    const int el = (HEADS == 8) ? (t >> 3) : t;
    const int EPP = 64 / HEADS;
    float ad = adst[dst * HEADS + hd];
    float m = -1e30f;
    for (int p = s + el; p < e; p += EPP){
      float v = asrc[col[p] * HEADS + hd] + ad;
      v = v > 0.0f ? v : 0.2f * v;
      m = fmaxf(m, v);
    }
    for (int off = HEADS; off < 64; off <<= 1) m = fmaxf(m, __shfl_xor(m, off));
    float sum = 0.0f;
    for (int p = s + el; p < e; p += EPP){
      float v = asrc[col[p] * HEADS + hd] + ad;
      v = v > 0.0f ? v : 0.2f * v;
      sum += __expf(v - m);
    }
    for (int off = HEADS; off < 64; off <<= 1) sum += __shfl_xor(sum, off);
    if (el == 0){ s_m[hd] = m; s_inv[hd] = 1.0f / (sum + 1e-16f); }
  }
  __syncthreads();

  int c0 = t * CPT;
  int hd = c0 / CH;
  float m = s_m[hd], inv = s_inv[hd];
  float ad = adst[dst * HEADS + hd];
  float acc[CPT] = {};
  int p = s;

  auto wgt = [&](int src) -> float {
    float v = asrc[src * HEADS + hd] + ad;
    v = v > 0.0f ? v : 0.2f * v;
    return __expf(v - m) * inv;
  };

  for (; p + 4 <= e; p += 4){
    int i0 = col[p], i1 = col[p+1], i2 = col[p+2], i3 = col[p+3];
    if (CPT == 8){
      union { uint4 u; f16 h[8]; } x0, x1, x2, x3;
      x0.u = *(const uint4*)(H + (size_t)i0 * F + c0);
      x1.u = *(const uint4*)(H + (size_t)i1 * F + c0);
      x2.u = *(const uint4*)(H + (size_t)i2 * F + c0);
      x3.u = *(const uint4*)(H + (size_t)i3 * F + c0);
      float w0 = wgt(i0), w1 = wgt(i1), w2 = wgt(i2), w3 = wgt(i3);
      #pragma unroll
      for (int i = 0; i < 8; i++)
        acc[i] += w0 * h2f(x0.h[i]) + w1 * h2f(x1.h[i])
                + w2 * h2f(x2.h[i]) + w3 * h2f(x3.h[i]);
    } else {
      union { u32 u; f16 h[2]; } x0, x1, x2, x3;
      x0.u = *(const u32*)(H + (size_t)i0 * F + c0);
      x1.u = *(const u32*)(H + (size_t)i1 * F + c0);
      x2.u = *(const u32*)(H + (size_t)i2 * F + c0);
      x3.u = *(const u32*)(H + (size_t)i3 * F + c0);
      float w0 = wgt(i0), w1 = wgt(i1), w2 = wgt(i2), w3 = wgt(i3);
      acc[0] += w0 * h2f(x0.h[0]) + w1 * h2f(x1.h[0]) + w2 * h2f(x2.h[0]) + w3 * h2f(x3.h[0]);
      acc[1] += w0 * h2f(x0.h[1]) + w1 * h2f(x1.h[1]) + w2 * h2f(x2.h[1]) + w3 * h2f(x3.h[1]);
    }
  }
  for (; p < e; p++){
    int src = col[p];
    float w0 = wgt(src);
    if (CPT == 8){
      union { uint4 u; f16 h[8]; } x;
      x.u = *(const uint4*)(H + (size_t)src * F + c0);
      #pragma unroll
      for (int i = 0; i < 8; i++) acc[i] += w0 * h2f(x.h[i]);
    } else {
      union { u32 u; f16 h[2]; } x;
      x.u = *(const u32*)(H + (size_t)src * F + c0);
      acc[0] += w0 * h2f(x.h[0]); acc[1] += w0 * h2f(x.h[1]);
    }
  }

  #pragma unroll
  for (int i = 0; i < CPT; i++){
    float v = acc[i] + bias[c0 + i];
    v = v > 0.0f ? v : 0.2f * v;
    size_t o = (size_t)dst * F + c0 + i;
    if (FINAL) Ofp[o] = v;
    else       Oh[o]  = f2h(v);
  }
}

// ---------------- launcher ----------------

extern "C" void kernel_launch(void* const* d_in, const int* in_sizes, int n_in,
                              void* d_out, int out_size, void* d_ws, size_t ws_size,
                              hipStream_t stream)
{
  const float* x    = (const float*)d_in[0];
  const int*   ei   = (const int*)d_in[1];
  const float* W_in = (const float*)d_in[2];
  const float* b_in = (const float*)d_in[3];
  const float* W1   = (const float*)d_in[4];
  const float* as1  = (const float*)d_in[5];
  const float* ad1  = (const float*)d_in[6];
  const float* b1   = (const float*)d_in[7];
  const float* W2   = (const float*)d_in[8];
  const float* as2  = (const float*)d_in[9];
  const float* ad2  = (const float*)d_in[10];
  const float* b2   = (const float*)d_in[11];
  const float* W3   = (const float*)d_in[12];
  const float* as3  = (const float*)d_in[13];
  const float* ad3  = (const float*)d_in[14];
  const float* b3   = (const float*)d_in[15];

  const int N  = in_sizes[0] / 32;   // 10000
  const int E  = in_sizes[1] / 2;    // 80000
  const int ET = E + N;
  const int MT = (N + 127) / 128;    // 79 row-tiles
  const int MP = MT * 128;           // 10112 padded rows

  char* w = (char*)d_ws;
  size_t off = 0;
  auto carve = [&](size_t bytes) -> char* {
    off = (off + 255) & ~(size_t)255;
    char* p = w + off;
    off += bytes;
    return p;
  };

  int* flag    = (int*)carve(4);
  int* cnt     = (int*)carve((size_t)N * 4);
  int* fillpos = (int*)carve((size_t)N * 4);
  int* row_ptr = (int*)carve((size_t)(N + 1) * 4);
  int* col     = (int*)carve((size_t)ET * 4);
  f16* xh      = (f16*)carve((size_t)MP * 32 * 2);
  f16* h0      = (f16*)carve((size_t)MP * 128 * 2);
  f16* Twin    = (f16*)carve((size_t)128 * 32 * 2);
  f16* T1      = (f16*)carve((size_t)2048 * 128 * 2);
  f16* T2      = (f16*)carve((size_t)2048 * 2048 * 2);
  f16* T3      = (f16*)carve((size_t)512 * 2048 * 2);
  f16* Hb      = (f16*)carve((size_t)MP * 2048 * 2);
  f16* H3      = (f16*)carve((size_t)MP * 512 * 2);
  f16* XB      = (f16*)carve((size_t)MP * 2048 * 2);
  float* asrc  = (float*)carve((size_t)N * 8 * 4);
  float* adst  = (float*)carve((size_t)N * 8 * 4);

  if (off > ws_size) return;

  float* out = (float*)d_out;
  const int nbx = (N * 32 + 255) / 256;          // 1250
  const int prep_grid = nbx + 4 + 256 + 4096 + 1024;
  const int lf_grid = ((E > N ? E : N) + 255) / 256;

  // prep: x->fp16 + all weight transposes (one launch)
  prep_kernel<<<prep_grid, 256, 0, stream>>>(x, xh, N * 32, nbx,
      W_in, Twin, W1, T1, W2, T2, W3, T3);

  // CSR build (4 launches)
  csr_init<<<(N + 255) / 256, 256, 0, stream>>>(ei, flag, cnt, fillpos, N);
  count_edges<<<(E + 255) / 256, 256, 0, stream>>>(ei, E, flag, cnt);
  scan_kernel<<<1, SCAN_T, 0, stream>>>(cnt, row_ptr, N);
  loop_fill<<<lf_grid, 256, 0, stream>>>(ei, E, flag, row_ptr, fillpos, col, N);

  // input projection: h0 = lrelu(x @ W_in + b_in) -> fp16  (K=32)
  gemm_kernel<1, 4, 32><<<MT * 1, 256, 0, stream>>>(xh, Twin, nullptr, h0, b_in,
      MP, 128, 32, MT, 1);

  // ---- GAT layer 1: 128 -> 8x256 ----
  gemm_kernel<2, 4, 32><<<MT * 16, 256, 0, stream>>>(h0, T1, nullptr, Hb, nullptr,
      MP, 2048, 128, MT, 16);
  alpha_kernel<8, 256><<<(N * 8 + 3) / 4, 256, 0, stream>>>(Hb, as1, ad1, asrc, adst, N);
  smax_agg_kernel<8, 256, false><<<N, 256, 0, stream>>>(Hb, row_ptr, col,
      asrc, adst, b1, XB, nullptr);

  // ---- GAT layer 2: 2048 -> 8x256 ----
  gemm_kernel<2, 4, 32><<<MT * 16, 256, 0, stream>>>(XB, T2, nullptr, Hb, nullptr,
      MP, 2048, 2048, MT, 16);
  alpha_kernel<8, 256><<<(N * 8 + 3) / 4, 256, 0, stream>>>(Hb, as2, ad2, asrc, adst, N);
  smax_agg_kernel<8, 256, false><<<N, 256, 0, stream>>>(Hb, row_ptr, col,
      asrc, adst, b2, XB, nullptr);

  // ---- GAT layer 3: 2048 -> 1x512 (FJ=2/BK=64, 632 blocks: R8 best) ----
  gemm_kernel<2, 2, 64><<<MT * 8, 256, 0, stream>>>(XB, T3, nullptr, H3, nullptr,
      MP, 512, 2048, MT, 8);
  alpha_kernel<1, 512><<<(N + 3) / 4, 256, 0, stream>>>(H3, as3, ad3, asrc, adst, N);
  smax_agg_kernel<1, 512, true><<<N, 256, 0, stream>>>(H3, row_ptr, col,
      asrc, adst, b3, nullptr, out);
}

// Round 14
// 353.942 us; speedup vs baseline: 1.0760x; 1.0760x over previous
//
#include <hip/hip_runtime.h>

typedef unsigned short u16;
typedef unsigned int u32;
typedef _Float16 f16;
typedef f16 f16x8 __attribute__((ext_vector_type(8)));
typedef float f32x4 __attribute__((ext_vector_type(4)));

__device__ __forceinline__ float h2f(f16 h){ return (float)h; }
__device__ __forceinline__ f16 f2h(float f){ return (f16)f; }

__device__ __forceinline__ f16x8 ldfrag(const f16* p){
  union { uint4 u; f16x8 h; } x;
  x.u = *(const uint4*)p;
  return x.h;
}
__device__ __forceinline__ void gload_lds16(const f16* g, f16* l){
  __builtin_amdgcn_global_load_lds(
      (const __attribute__((address_space(1))) u32*)g,
      (__attribute__((address_space(3))) u32*)l, 16, 0, 0);
}

template<int N> __device__ __forceinline__ void wait_vmcnt(){
  if constexpr      (N == 0) asm volatile("s_waitcnt vmcnt(0)" ::: "memory");
  else if constexpr (N == 4) asm volatile("s_waitcnt vmcnt(4)" ::: "memory");
  else if constexpr (N == 6) asm volatile("s_waitcnt vmcnt(6)" ::: "memory");
  else if constexpr (N == 8) asm volatile("s_waitcnt vmcnt(8)" ::: "memory");
  else static_assert(N == 0, "unsupported vmcnt");
}

// ---------------- CSR build (merged) ----------------

__global__ void csr_init(const int* __restrict__ ei, int* __restrict__ flag,
                         int* __restrict__ cnt, int* __restrict__ fillpos, int n){
  int i = blockIdx.x * blockDim.x + threadIdx.x;
  if (i == 0){
    int orv = 0;
    for (int k = 0; k < 200; k++) orv |= ei[2*k + 1];
    *flag = (orv == 0) ? 1 : 0;      // int64 edge_index -> high words all 0
  }
  if (i < n){ cnt[i] = 1; fillpos[i] = 1; }   // slot 0 = self loop
}

__global__ void count_edges(const int* __restrict__ ei, int E, const int* __restrict__ flag,
                            int* __restrict__ cnt){
  int e = blockIdx.x * blockDim.x + threadIdx.x;
  if (e >= E) return;
  int dst = (*flag) ? ei[2*E + 2*e] : ei[E + e];
  atomicAdd(&cnt[dst], 1);
}

#define SCAN_T 1024
__global__ void scan_kernel(const int* __restrict__ cnt, int* __restrict__ row_ptr, int n){
  __shared__ int sm[SCAN_T];
  int t = threadIdx.x;
  int chunk = (n + SCAN_T - 1) / SCAN_T;
  int lo = t * chunk, hi = lo + chunk; if (hi > n) hi = n; if (lo > n) lo = n;
  int s = 0;
  for (int i = lo; i < hi; i++) s += cnt[i];
  sm[t] = s; __syncthreads();
  for (int off = 1; off < SCAN_T; off <<= 1){
    int v = (t >= off) ? sm[t - off] : 0;
    __syncthreads();
    sm[t] += v;
    __syncthreads();
  }
  int base = sm[t] - s;
  for (int i = lo; i < hi; i++){ row_ptr[i] = base; base += cnt[i]; }
  if (t == 0) row_ptr[n] = sm[SCAN_T - 1];
}

__global__ void loop_fill(const int* __restrict__ ei, int E, const int* __restrict__ flag,
                          const int* __restrict__ row_ptr, int* __restrict__ fillpos,
                          int* __restrict__ col, int n){
  int i = blockIdx.x * blockDim.x + threadIdx.x;
  if (i < n) col[row_ptr[i]] = i;          // self loop at slot 0
  if (i < E){
    int f = *flag;
    int src = f ? ei[2*i]       : ei[i];
    int dst = f ? ei[2*E + 2*i] : ei[E + i];
    int off = atomicAdd(&fillpos[dst], 1); // starts at 1: disjoint from slot 0
    col[row_ptr[dst] + off] = src;
  }
}

// ---------------- merged prep: x->fp16 + all 4 weight transposes ----------

__global__ __launch_bounds__(256) void prep_kernel(
    const float* __restrict__ x, f16* __restrict__ xh, int nx, int nbx,
    const float* __restrict__ Win, f16* __restrict__ Twin,
    const float* __restrict__ W1, f16* __restrict__ T1,
    const float* __restrict__ W2, f16* __restrict__ T2,
    const float* __restrict__ W3, f16* __restrict__ T3)
{
  int b = blockIdx.x;
  int tid = threadIdx.x;
  if (b < nbx){
    int i = b * 256 + tid;
    if (i < nx) xh[i] = f2h(x[i]);
    return;
  }
  b -= nbx;
  const float* W; f16* T; int K, N;
  if (b < 4)              { W = Win; T = Twin; K = 32;   N = 128;  }
  else if ((b -= 4) < 256){ W = W1;  T = T1;   K = 128;  N = 2048; }
  else if ((b -= 256) < 4096){ W = W2; T = T2; K = 2048; N = 2048; }
  else { b -= 4096;         W = W3;  T = T3;   K = 2048; N = 512;  }
  int kbn = K / 32;
  int kb = (b % kbn) * 32, nb = (b / kbn) * 32;
  __shared__ float sm[32][33];
  int tx = tid & 31, ty = tid >> 5;
  for (int i = 0; i < 32; i += 8)
    sm[ty + i][tx] = W[(size_t)(kb + ty + i) * N + nb + tx];
  __syncthreads();
  for (int i = 0; i < 32; i += 8)
    T[(size_t)(nb + ty + i) * K + kb + tx] = f2h(sm[tx][ty + i]);
}

// ---------------- fp16 MFMA GEMM, dbuf + counted vmcnt, swizzled ----------
// R12 champion configuration (355.5us). 128 x (FJ*32) tile, 4 waves 2x2,
// depth-2 double-buffer, counted vmcnt(NL). BK=32 big-N, BK=64/FJ=2 N=512.
// CLOSED lines (all measured null/regress): BK=64 on big-N (R8 -3%),
// depth-3 (R13 null + LDS cost), fused-alpha (R4 atomics / R11 registers),
// 8-phase (doesn't quantize: M=10112 -> 320 blocks @128KB = 1/CU).
// Swizzle both-sides (rule #21): SQ_LDS_BANK_CONFLICT = 0 (R7-R13).
// EPI 0: fp32 C.  EPI 1: bias+lrelu -> fp16.  EPI 2: plain fp16.

template<int EPI, int FJ, int BK>
__global__ __launch_bounds__(256) void gemm_kernel(
    const f16* __restrict__ A, const f16* __restrict__ B,
    float* __restrict__ C, f16* __restrict__ Ch,
    const float* __restrict__ bias,
    int M, int N, int K, int nbm, int nbn)
{
  constexpr int BN  = FJ * 32;
  constexpr int TPR = BK / 8;
  constexpr int RPG = 256 / TPR;
  constexpr int NGA = 128 / RPG;
  constexpr int NGB = BN / RPG;
  constexpr int KS  = BK / 32;
  constexpr int NL  = NGA + NGB;

  __shared__ f16 sA[2][128 * BK];
  __shared__ f16 sB[2][BN * BK];

  // bijective XCD swizzle (m204)
  int nwg = nbm * nbn;
  int bid = blockIdx.x;
  int q = nwg >> 3, r = nwg & 7;
  int xcd = bid & 7, idx = bid >> 3;
  int wg = (xcd < r ? xcd * (q + 1) : r * (q + 1) + (xcd - r) * q) + idx;
  int bm = wg / nbn, bn = wg % nbn;

  int tid = threadIdx.x;
  int lane = tid & 63;
  int w = tid >> 6;
  int wr = (w >> 1) * 64, wc = (w & 1) * (FJ * 16);
  int lm = lane & 15;

  int slot = tid % TPR, rg = tid / TPR;
  int sk;
  if constexpr (BK == 64) sk = ((slot ^ (rg & 7))) * 8;
  else                    sk = ((slot ^ ((rg >> 1) & 3))) * 8;

  const f16* pA[NGA];
  const f16* pB[NGB];
  #pragma unroll
  for (int i = 0; i < NGA; i++)
    pA[i] = A + ((long)bm * 128 + rg + RPG * i) * K + sk;
  #pragma unroll
  for (int i = 0; i < NGB; i++)
    pB[i] = B + ((long)bn * BN + rg + RPG * i) * K + sk;

  auto STAGE = [&](int buf, int k0){
    #pragma unroll
    for (int i = 0; i < NGA; i++)
      gload_lds16(pA[i] + k0, &sA[buf][i * 2048 + tid * 8]);
    #pragma unroll
    for (int i = 0; i < NGB; i++)
      gload_lds16(pB[i] + k0, &sB[buf][i * 2048 + tid * 8]);
  };

  f32x4 acc[4][FJ] = {};

  int nt = K / BK;
  STAGE(0, 0);
  int cur = 0;
  for (int t = 0; t < nt; t++){
    if (t + 1 < nt){
      STAGE(cur ^ 1, (t + 1) * BK);
      wait_vmcnt<NL>();
    } else {
      wait_vmcnt<0>();
    }
    __builtin_amdgcn_s_barrier();
    __builtin_amdgcn_sched_barrier(0);

    f16x8 af[4][KS], bfr[FJ][KS];
    #pragma unroll
    for (int ks = 0; ks < KS; ks++){
      #pragma unroll
      for (int f = 0; f < 4; f++){
        int row = wr + f * 16 + lm;
        int phys;
        if constexpr (BK == 64) phys = (ks * 4 + (lane >> 4)) ^ (lm & 7);
        else                    phys = (lane >> 4) ^ ((lm >> 1) & 3);
        af[f][ks] = ldfrag(&sA[cur][row * BK + phys * 8]);
      }
      #pragma unroll
      for (int f = 0; f < FJ; f++){
        int row = wc + f * 16 + lm;
        int phys;
        if constexpr (BK == 64) phys = (ks * 4 + (lane >> 4)) ^ (lm & 7);
        else                    phys = (lane >> 4) ^ ((lm >> 1) & 3);
        bfr[f][ks] = ldfrag(&sB[cur][row * BK + phys * 8]);
      }
    }
    __builtin_amdgcn_s_setprio(1);
    #pragma unroll
    for (int ks = 0; ks < KS; ks++)
      #pragma unroll
      for (int fi = 0; fi < 4; fi++)
        #pragma unroll
        for (int fj = 0; fj < FJ; fj++)
          acc[fi][fj] = __builtin_amdgcn_mfma_f32_16x16x32_f16(
              af[fi][ks], bfr[fj][ks], acc[fi][fj], 0, 0, 0);
    __builtin_amdgcn_s_setprio(0);
    __builtin_amdgcn_sched_barrier(0);
    __builtin_amdgcn_s_barrier();
    cur ^= 1;
  }

  // ---- store epilogue (M padded: no guards) ----
  #pragma unroll
  for (int fi = 0; fi < 4; fi++){
    int mb = bm * 128 + wr + fi * 16 + ((lane >> 4) << 2);
    #pragma unroll
    for (int fj = 0; fj < FJ; fj++){
      int n = bn * BN + wc + fj * 16 + lm;
      #pragma unroll
      for (int j = 0; j < 4; j++){
        int m = mb + j;
        float v = acc[fi][fj][j];
        size_t o = (size_t)m * N + n;
        if (EPI == 0){
          C[o] = v;
        } else if (EPI == 2){
          Ch[o] = f2h(v);
        } else {
          v += bias[n];
          v = v > 0.0f ? v : 0.2f * v;
          Ch[o] = f2h(v);
        }
      }
    }
  }
}

// ---------------- attention coefficients (fp16 H) ----------------

template<int HEADS, int CH>
__global__ __launch_bounds__(256) void alpha_kernel(
    const f16* __restrict__ H, const float* __restrict__ a_s, const float* __restrict__ a_d,
    float* __restrict__ asrc, float* __restrict__ adst, int Nn)
{
  int gw = blockIdx.x * 4 + (threadIdx.x >> 6);
  int lane = threadIdx.x & 63;
  int node = gw / HEADS, hd = gw % HEADS;
  if (node >= Nn) return;
  size_t base = (size_t)node * HEADS * CH + hd * CH;
  const float* asp = a_s + hd * CH;
  const float* adp = a_d + hd * CH;
  float s1 = 0.0f, s2 = 0.0f;
  #pragma unroll
  for (int i = 0; i < CH / 256; i++){
    int off = i * 256 + lane * 4;
    union { uint2 u; f16 h[4]; } x;
    x.u = *(const uint2*)(H + base + off);
    float4 s4 = *(const float4*)(asp + off);
    float4 d4 = *(const float4*)(adp + off);
    s1 += h2f(x.h[0]) * s4.x + h2f(x.h[1]) * s4.y + h2f(x.h[2]) * s4.z + h2f(x.h[3]) * s4.w;
    s2 += h2f(x.h[0]) * d4.x + h2f(x.h[1]) * d4.y + h2f(x.h[2]) * d4.z + h2f(x.h[3]) * d4.w;
  }
  for (int off = 32; off; off >>= 1){
    s1 += __shfl_xor(s1, off);
    s2 += __shfl_xor(s2, off);
  }
  if (lane == 0){ asrc[gw] = s1; adst[gw] = s2; }
}

// ---------------- fused segment-softmax + aggregation ----------------
// Phase A (HEADS=8): all 256 threads, 32-lane group per head (butterfly
// reduce stays within the aligned 32-lane half-wave). Was wave-0-only:
// 192 threads idled through 2 dependent-load rounds.

template<int HEADS, int CH, bool FINAL>
__global__ __launch_bounds__(256) void smax_agg_kernel(
    const f16* __restrict__ H, const int* __restrict__ row_ptr,
    const int* __restrict__ col,
    const float* __restrict__ asrc, const float* __restrict__ adst,
    const float* __restrict__ bias, f16* __restrict__ Oh, float* __restrict__ Ofp)
{
  constexpr int F = HEADS * CH;
  constexpr int CPT = F / 256;
  __shared__ float s_m[HEADS], s_inv[HEADS];
  int dst = blockIdx.x;
  int t = threadIdx.x;
  int s = row_ptr[dst], e = row_ptr[dst + 1];

  if (HEADS == 8){
    int hd = t >> 5;                 // 8 groups of 32 lanes
    int el = t & 31;
    float ad = adst[dst * HEADS + hd];
    float m = -1e30f;
    for (int p = s + el; p < e; p += 32){
      float v = asrc[col[p] * HEADS + hd] + ad;
      v = v > 0.0f ? v : 0.2f * v;
      m = fmaxf(m, v);
    }
    #pragma unroll
    for (int off = 1; off < 32; off <<= 1) m = fmaxf(m, __shfl_xor(m, off));
    float sum = 0.0f;
    for (int p = s + el; p < e; p += 32){
      float v = asrc[col[p] * HEADS + hd] + ad;
      v = v > 0.0f ? v : 0.2f * v;
      sum += __expf(v - m);
    }
    #pragma unroll
    for (int off = 1; off < 32; off <<= 1) sum += __shfl_xor(sum, off);
    if (el == 0){ s_m[hd] = m; s_inv[hd] = 1.0f / (sum + 1e-16f); }
  } else if (t < 64){
    float ad = adst[dst];
    float m = -1e30f;
    for (int p = s + t; p < e; p += 64){
      float v = asrc[col[p]] + ad;
      v = v > 0.0f ? v : 0.2f * v;
      m = fmaxf(m, v);
    }
    for (int off = 1; off < 64; off <<= 1) m = fmaxf(m, __shfl_xor(m, off));
    float sum = 0.0f;
    for (int p = s + t; p < e; p += 64){
      float v = asrc[col[p]] + ad;
      v = v > 0.0f ? v : 0.2f * v;
      sum += __expf(v - m);
    }
    for (int off = 1; off < 64; off <<= 1) sum += __shfl_xor(sum, off);
    if (t == 0){ s_m[0] = m; s_inv[0] = 1.0f / (sum + 1e-16f); }
  }
  __syncthreads();

  int c0 = t * CPT;
  int hd = c0 / CH;
  float m = s_m[hd], inv = s_inv[hd];
  float ad = adst[dst * HEADS + hd];
  float acc[CPT] = {};
  int p = s;

  auto wgt = [&](int src) -> float {
    float v = asrc[src * HEADS + hd] + ad;
    v = v > 0.0f ? v : 0.2f * v;
    return __expf(v - m) * inv;
  };

  for (; p + 4 <= e; p += 4){
    int i0 = col[p], i1 = col[p+1], i2 = col[p+2], i3 = col[p+3];
    if (CPT == 8){
      union { uint4 u; f16 h[8]; } x0, x1, x2, x3;
      x0.u = *(const uint4*)(H + (size_t)i0 * F + c0);
      x1.u = *(const uint4*)(H + (size_t)i1 * F + c0);
      x2.u = *(const uint4*)(H + (size_t)i2 * F + c0);
      x3.u = *(const uint4*)(H + (size_t)i3 * F + c0);
      float w0 = wgt(i0), w1 = wgt(i1), w2 = wgt(i2), w3 = wgt(i3);
      #pragma unroll
      for (int i = 0; i < 8; i++)
        acc[i] += w0 * h2f(x0.h[i]) + w1 * h2f(x1.h[i])
                + w2 * h2f(x2.h[i]) + w3 * h2f(x3.h[i]);
    } else {
      union { u32 u; f16 h[2]; } x0, x1, x2, x3;
      x0.u = *(const u32*)(H + (size_t)i0 * F + c0);
      x1.u = *(const u32*)(H + (size_t)i1 * F + c0);
      x2.u = *(const u32*)(H + (size_t)i2 * F + c0);
      x3.u = *(const u32*)(H + (size_t)i3 * F + c0);
      float w0 = wgt(i0), w1 = wgt(i1), w2 = wgt(i2), w3 = wgt(i3);
      acc[0] += w0 * h2f(x0.h[0]) + w1 * h2f(x1.h[0]) + w2 * h2f(x2.h[0]) + w3 * h2f(x3.h[0]);
      acc[1] += w0 * h2f(x0.h[1]) + w1 * h2f(x1.h[1]) + w2 * h2f(x2.h[1]) + w3 * h2f(x3.h[1]);
    }
  }
  for (; p < e; p++){
    int src = col[p];
    float w0 = wgt(src);
    if (CPT == 8){
      union { uint4 u; f16 h[8]; } x;
      x.u = *(const uint4*)(H + (size_t)src * F + c0);
      #pragma unroll
      for (int i = 0; i < 8; i++) acc[i] += w0 * h2f(x.h[i]);
    } else {
      union { u32 u; f16 h[2]; } x;
      x.u = *(const u32*)(H + (size_t)src * F + c0);
      acc[0] += w0 * h2f(x.h[0]); acc[1] += w0 * h2f(x.h[1]);
    }
  }

  #pragma unroll
  for (int i = 0; i < CPT; i++){
    float v = acc[i] + bias[c0 + i];
    v = v > 0.0f ? v : 0.2f * v;
    size_t o = (size_t)dst * F + c0 + i;
    if (FINAL) Ofp[o] = v;
    else       Oh[o]  = f2h(v);
  }
}

// ---------------- launcher ----------------

extern "C" void kernel_launch(void* const* d_in, const int* in_sizes, int n_in,
                              void* d_out, int out_size, void* d_ws, size_t ws_size,
                              hipStream_t stream)
{
  const float* x    = (const float*)d_in[0];
  const int*   ei   = (const int*)d_in[1];
  const float* W_in = (const float*)d_in[2];
  const float* b_in = (const float*)d_in[3];
  const float* W1   = (const float*)d_in[4];
  const float* as1  = (const float*)d_in[5];
  const float* ad1  = (const float*)d_in[6];
  const float* b1   = (const float*)d_in[7];
  const float* W2   = (const float*)d_in[8];
  const float* as2  = (const float*)d_in[9];
  const float* ad2  = (const float*)d_in[10];
  const float* b2   = (const float*)d_in[11];
  const float* W3   = (const float*)d_in[12];
  const float* as3  = (const float*)d_in[13];
  const float* ad3  = (const float*)d_in[14];
  const float* b3   = (const float*)d_in[15];

  const int N  = in_sizes[0] / 32;   // 10000
  const int E  = in_sizes[1] / 2;    // 80000
  const int ET = E + N;
  const int MT = (N + 127) / 128;    // 79 row-tiles
  const int MP = MT * 128;           // 10112 padded rows

  char* w = (char*)d_ws;
  size_t off = 0;
  auto carve = [&](size_t bytes) -> char* {
    off = (off + 255) & ~(size_t)255;
    char* p = w + off;
    off += bytes;
    return p;
  };

  int* flag    = (int*)carve(4);
  int* cnt     = (int*)carve((size_t)N * 4);
  int* fillpos = (int*)carve((size_t)N * 4);
  int* row_ptr = (int*)carve((size_t)(N + 1) * 4);
  int* col     = (int*)carve((size_t)ET * 4);
  f16* xh      = (f16*)carve((size_t)MP * 32 * 2);
  f16* h0      = (f16*)carve((size_t)MP * 128 * 2);
  f16* Twin    = (f16*)carve((size_t)128 * 32 * 2);
  f16* T1      = (f16*)carve((size_t)2048 * 128 * 2);
  f16* T2      = (f16*)carve((size_t)2048 * 2048 * 2);
  f16* T3      = (f16*)carve((size_t)512 * 2048 * 2);
  f16* Hb      = (f16*)carve((size_t)MP * 2048 * 2);
  f16* H3      = (f16*)carve((size_t)MP * 512 * 2);
  f16* XB      = (f16*)carve((size_t)MP * 2048 * 2);
  float* asrc  = (float*)carve((size_t)N * 8 * 4);
  float* adst  = (float*)carve((size_t)N * 8 * 4);

  if (off > ws_size) return;

  float* out = (float*)d_out;
  const int nbx = (N * 32 + 255) / 256;          // 1250
  const int prep_grid = nbx + 4 + 256 + 4096 + 1024;
  const int lf_grid = ((E > N ? E : N) + 255) / 256;

  // prep: x->fp16 + all weight transposes (one launch)
  prep_kernel<<<prep_grid, 256, 0, stream>>>(x, xh, N * 32, nbx,
      W_in, Twin, W1, T1, W2, T2, W3, T3);

  // CSR build (4 launches)
  csr_init<<<(N + 255) / 256, 256, 0, stream>>>(ei, flag, cnt, fillpos, N);
  count_edges<<<(E + 255) / 256, 256, 0, stream>>>(ei, E, flag, cnt);
  scan_kernel<<<1, SCAN_T, 0, stream>>>(cnt, row_ptr, N);
  loop_fill<<<lf_grid, 256, 0, stream>>>(ei, E, flag, row_ptr, fillpos, col, N);

  // input projection: h0 = lrelu(x @ W_in + b_in) -> fp16  (K=32)
  gemm_kernel<1, 4, 32><<<MT * 1, 256, 0, stream>>>(xh, Twin, nullptr, h0, b_in,
      MP, 128, 32, MT, 1);

  // ---- GAT layer 1: 128 -> 8x256 ----
  gemm_kernel<2, 4, 32><<<MT * 16, 256, 0, stream>>>(h0, T1, nullptr, Hb, nullptr,
      MP, 2048, 128, MT, 16);
  alpha_kernel<8, 256><<<(N * 8 + 3) / 4, 256, 0, stream>>>(Hb, as1, ad1, asrc, adst, N);
  smax_agg_kernel<8, 256, false><<<N, 256, 0, stream>>>(Hb, row_ptr, col,
      asrc, adst, b1, XB, nullptr);

  // ---- GAT layer 2: 2048 -> 8x256 ----
  gemm_kernel<2, 4, 32><<<MT * 16, 256, 0, stream>>>(XB, T2, nullptr, Hb, nullptr,
      MP, 2048, 2048, MT, 16);
  alpha_kernel<8, 256><<<(N * 8 + 3) / 4, 256, 0, stream>>>(Hb, as2, ad2, asrc, adst, N);
  smax_agg_kernel<8, 256, false><<<N, 256, 0, stream>>>(Hb, row_ptr, col,
      asrc, adst, b2, XB, nullptr);

  // ---- GAT layer 3: 2048 -> 1x512 (FJ=2/BK=64, 632 blocks: R8 best) ----
  gemm_kernel<2, 2, 64><<<MT * 8, 256, 0, stream>>>(XB, T3, nullptr, H3, nullptr,
      MP, 512, 2048, MT, 8);
  alpha_kernel<1, 512><<<(N + 3) / 4, 256, 0, stream>>>(H3, as3, ad3, asrc, adst, N);
  smax_agg_kernel<1, 512, true><<<N, 256, 0, stream>>>(H3, row_ptr, col,
      asrc, adst, b3, nullptr, out);
}